// Round 8
// baseline (206.412 us; speedup 1.0000x reference)
//
#include <hip/hip_runtime.h>

// NonImagingRod: per-ray damped-Newton (LM) root find on f(t) = A t^2 + B t + C.
// Round-17: GRID-OVERSUBSCRIPTION DE-PHASING. Ten structurally different
// kernels (R8-R16: flat/pipelined/chunked, coalesced/not, 4/8/16 rays/thread,
// packed/scalar) ALL pin at 40-44us, VALUBusy 43-54%. Shared trait: every
// wave starts at t=0, issues all loads, waits -> grid-wide phase lock makes
// T_mem and T_compute additive. Intra-thread scheduling can't break it
// (R15: compiler sinks between-phase loads; R16: chunked vmcnt neutral).
// Fix: 2 rays/thread -> 8192 blocks = ~4 residency rounds. Later blocks
// launch as slots free -> steady-state CU mix has loaders + computers
// coexisting; round k compute hides round k+1 loads. Hardware-scheduled
// overlap, no compiler cooperation needed.
// Per-thread code = R13-proven minimal shape: 4x dwordx3 (strided ray->lane,
// lane-contiguous 768B windows), setup, iterate31, f64 accum.
//
// Predicted: rod 41.6 -> 27-33us, VALUBusy 62-80%, Occupancy up, FETCH
// ~49-52MB, WRITE <=256B, VGPR ~32, absmax 0.0.
// Falsifier: flat 40-43us despite staggered rounds -> genuine read-path /
// issue ceiling for this op; declare ROOFLINE.
//
// Codegen notes (hard-won, R2-R16):
//  - Loads issued BETWEEN compute phases get SUNK (R15). Aggregate pipeline
//    state -> scratch (R14, 24MB WRITE). Keep loads contiguous at the top.
//  - Strided ray->lane map + float3 = compulsory-only transactions (R13 win:
//    blocked AoS float4 was 3x lines, though wall-neutral in lockstep).
//  - scalar iterate (4 fma + 2 mul + 1 rcp per ray) is the proven shape; no
//    double-rate packed fp32 on gfx950. global_load_lds staging kills MLP.
//  - No-spill signature: FETCH ~49-50MB, WRITE ~32-256B.
//  - Clamp(+-1000) provably inactive; rcp ~1ulp fine (absmax 0.0, R2-R16).

#define LM_ITERS 31
constexpr float DAMPING = 0.5f;

struct F3 { float x, y, z; };   // 12B, 4-aligned -> global_load_dwordx3

__global__ __launch_bounds__(256) void rod_kernel(
    const float* __restrict__ P, const float* __restrict__ V,
    const float* __restrict__ Rm, const float* __restrict__ Tv,
    const float* __restrict__ c_ptr, double* __restrict__ ws, int n)
{
    const float c  = c_ptr[0];
    const float r00 = Rm[0], r01 = Rm[1], r02 = Rm[2];
    const float r10 = Rm[3], r11 = Rm[4], r12 = Rm[5];
    const float r20 = Rm[6], r21 = Rm[7], r22 = Rm[8];
    const float t0 = Tv[0], t1 = Tv[1], t2 = Tv[2];

    const int lane = threadIdx.x & 63;
    const int wave = threadIdx.x >> 6;
    // wave owns 128 consecutive rays; lane's 2 rays strided (lane, 64+lane):
    // every load instr reads a 768B lane-contiguous window (R13-proven).
    const int wbase = (blockIdx.x * 4 + wave) * 128;

    const F3* __restrict__ P3 = (const F3*)P;
    const F3* __restrict__ V3 = (const F3*)V;

    float px[2], py[2], pz[2], vx[2], vy[2], vz[2];

    if (wbase + 128 <= n) {
        // 4 x dwordx3, all in flight together (full MLP, nothing to sink)
        #pragma unroll
        for (int r = 0; r < 2; ++r) {
            const F3 p = P3[wbase + 64 * r + lane];
            px[r] = p.x; py[r] = p.y; pz[r] = p.z;
        }
        #pragma unroll
        for (int r = 0; r < 2; ++r) {
            const F3 v = V3[wbase + 64 * r + lane];
            vx[r] = v.x; vy[r] = v.y; vz[r] = v.z;
        }
    } else {
        // tail fallback (n=4M is an exact multiple of 128; kept for safety)
        #pragma unroll
        for (int r = 0; r < 2; ++r) {
            const int ray = wbase + 64 * r + lane;
            if (ray < n) {
                px[r] = P[3 * ray + 0]; py[r] = P[3 * ray + 1]; pz[r] = P[3 * ray + 2];
                vx[r] = V[3 * ray + 0]; vy[r] = V[3 * ray + 1]; vz[r] = V[3 * ray + 2];
            } else {
                px[r] = py[r] = pz[r] = 0.0f;
                vx[r] = vy[r] = vz[r] = 0.0f;
            }
        }
    }

    // ---- per-ray setup: rigid inverse transform, quadratic coefficients ----
    float nA[2], f[2], fp[2];
    #pragma unroll
    for (int r = 0; r < 2; ++r) {
        const float ax = px[r] - t0, ay = py[r] - t1, az = pz[r] - t2;
        const float plx = ax * r00 + ay * r10 + az * r20;
        const float ply = ax * r01 + ay * r11 + az * r21;
        const float plz = ax * r02 + ay * r12 + az * r22;
        const float vlx = vx[r] * r00 + vy[r] * r10 + vz[r] * r20;
        const float vly = vx[r] * r01 + vy[r] * r11 + vz[r] * r21;
        const float vlz = vx[r] * r02 + vy[r] * r12 + vz[r] * r22;
        nA[r] = c * (vly * vly + vlz * vlz);                 // -A
        f[r]  = plx - c * (ply * ply + plz * plz);           // f(0)  = C
        fp[r] = vlx - 2.0f * c * (ply * vly + plz * vlz);    // f'(0) = B
    }

    // delta = f*f'/(f'^2+damping); tmp = f' - A*delta;
    // f <- f - delta*tmp (exact quadratic); f' <- tmp - A*delta.
    #pragma unroll 1
    for (int it = 0; it < LM_ITERS; ++it) {
        #pragma unroll
        for (int r = 0; r < 2; ++r) {
            const float den = fmaf(fp[r], fp[r], DAMPING);
            const float rcp = __builtin_amdgcn_rcpf(den);  // ~1 ulp; LM self-corrects
            const float d   = (f[r] * fp[r]) * rcp;
            const float tmp = fmaf(nA[r], d, fp[r]);
            f[r]  = fmaf(-d, tmp, f[r]);
            fp[r] = fmaf(nA[r], d, tmp);
        }
    }

    // ---- accumulate sum of f^2 over this thread's 2 rays (f64) ----
    double acc = 0.0;
    #pragma unroll
    for (int r = 0; r < 2; ++r)
        if (wbase + 64 * r + lane < n) acc += (double)f[r] * (double)f[r];

    // wave(64) shuffle reduce -> LDS across 4 waves -> one f64 atomic per block
    for (int off = 32; off > 0; off >>= 1)
        acc += __shfl_down(acc, off, 64);
    __shared__ double sacc[4];
    if (lane == 0) sacc[wave] = acc;
    __syncthreads();
    if (threadIdx.x == 0) {
        atomicAdd(ws, sacc[0] + sacc[1] + sacc[2] + sacc[3]);
    }
}

__global__ void rod_finalize(const double* __restrict__ ws,
                             const float* __restrict__ loss_in,
                             float* __restrict__ out, double inv_n)
{
    out[0] = (float)(ws[0] * inv_n + (double)loss_in[0]);
}

extern "C" void kernel_launch(void* const* d_in, const int* in_sizes, int n_in,
                              void* d_out, int out_size, void* d_ws, size_t ws_size,
                              hipStream_t stream) {
    const float* P       = (const float*)d_in[0];
    const float* V       = (const float*)d_in[1];
    const float* R       = (const float*)d_in[2];
    const float* T       = (const float*)d_in[3];
    const float* c       = (const float*)d_in[4];
    const float* loss_in = (const float*)d_in[5];

    const int n = in_sizes[0] / 3;           // number of rays

    // d_ws is poisoned to 0xAA before every launch — zero the accumulator.
    hipMemsetAsync(d_ws, 0, sizeof(double), stream);

    // 2 rays/thread -> 8192 blocks = ~4 residency rounds. Oversubscription
    // staggers block start times so loads of later blocks hide under compute
    // of earlier ones (breaks the grid-wide load/compute phase lock).
    const int threads = (n + 1) / 2;
    const int block   = 256;
    const int grid    = (threads + block - 1) / block;
    rod_kernel<<<grid, block, 0, stream>>>(P, V, R, T, c, (double*)d_ws, n);
    rod_finalize<<<1, 1, 0, stream>>>((const double*)d_ws, loss_in,
                                      (float*)d_out, 1.0 / (double)n);
}